// Round 9
// baseline (814.823 us; speedup 1.0000x reference)
//
#include <hip/hip_runtime.h>

// ---------------- types & helpers ----------------
typedef __attribute__((ext_vector_type(4))) float  f32x4;
typedef __attribute__((ext_vector_type(8))) short  s16x8;

__device__ __forceinline__ short f2bf(float f) {
    unsigned u = __builtin_bit_cast(unsigned, f);
    u += 0x7FFFu + ((u >> 16) & 1u);            // round-to-nearest-even
    return (short)(u >> 16);
}
__device__ __forceinline__ float bf2f(short s) {
    unsigned u = ((unsigned)(unsigned short)s) << 16;
    return __builtin_bit_cast(float, u);
}

// raw barrier: LDS ordering only — does NOT drain vmcnt, so register-destined
// global prefetch loads stay in flight across it (hipcc's __syncthreads drains
// vmcnt(0), defeating cross-phase prefetch).
#define BAR() do { asm volatile("s_waitcnt lgkmcnt(0)" ::: "memory"); \
                   __builtin_amdgcn_s_barrier(); } while (0)

#define DEPTH 128   // D == H*C == 128
#define HEADS 8
#define TILE_N 64   // node_proj tile
#define TILE_E 64   // fused_edge tile (r6 best)
#define NBLK 2048   // fused_edge grid (multiple of 8 XCDs)

// ---------------- kernel 0: W -> bf16, transposed (Wt[c][k]) ----------------
// order: 0=Wq 1=Wk 2=Wv 3=We 4=Wskip
__global__ void prep_w(const float* __restrict__ Wq, const float* __restrict__ Wk,
                       const float* __restrict__ Wv, const float* __restrict__ We,
                       const float* __restrict__ Wsk, short* __restrict__ Wt5) {
    int idx = blockIdx.x * 256 + threadIdx.x;
    if (idx >= 5 * DEPTH * DEPTH) return;
    int mat = idx >> 14;
    int rem = idx & 16383;
    int k = rem >> 7, c = rem & 127;
    const float* W = (mat == 0) ? Wq : (mat == 1) ? Wk : (mat == 2) ? Wv : (mat == 3) ? We : Wsk;
    Wt5[mat * 16384 + c * 128 + k] = f2bf(W[k * 128 + c]);
}

// ---------------- shared GEMM pieces ----------------
#define LOAD_BFRAG(bfrag, Wt, wc, lane)                                         \
    _Pragma("unroll") for (int nt_ = 0; nt_ < 4; nt_++)                         \
    _Pragma("unroll") for (int kk_ = 0; kk_ < 4; kk_++) {                       \
        int col_ = (wc) + nt_ * 16 + ((lane) & 15);                             \
        int kidx_ = kk_ * 32 + ((lane) >> 4) * 8;                               \
        bfrag[nt_][kk_] = *(const s16x8*)&(Wt)[col_ * 128 + kidx_];             \
    }

// ---------------- kernel 1: node projections (single pass, all 4 mats) ----------------
__global__ __launch_bounds__(512, 1) void node_proj(
    const float* __restrict__ x, const short* __restrict__ Wt5,
    const float* __restrict__ bq, const float* __restrict__ bk,
    const float* __restrict__ bv, const float* __restrict__ bsk,
    short* __restrict__ qb, short* __restrict__ kb, short* __restrict__ vb,
    float* __restrict__ skb, int Nn) {
    __shared__ short Asm[TILE_N][136];
    int tid = threadIdx.x, wave = tid >> 6, lane = tid & 63;
    int row0 = blockIdx.x * TILE_N;

    for (int i_ = 0; i_ < 4; i_++) {
        int f_ = tid + i_ * 512;
        int r_ = f_ >> 5, c4_ = f_ & 31;
        int gr_ = row0 + r_;
        float4 v_ = (gr_ < Nn) ? ((const float4*)x)[(size_t)gr_ * 32 + c4_]
                               : make_float4(0.f, 0.f, 0.f, 0.f);
        short* d_ = &Asm[r_][c4_ * 4];
        d_[0] = f2bf(v_.x); d_[1] = f2bf(v_.y); d_[2] = f2bf(v_.z); d_[3] = f2bf(v_.w);
    }
    __syncthreads();

    int wr = (wave >> 1) * 16, wc = (wave & 1) * 64;

    for (int mat = 0; mat < 4; mat++) {
        const short* Wt = Wt5 + ((mat < 3) ? mat : 4) * 16384;
        const float* bias = (mat == 0) ? bq : (mat == 1) ? bk : (mat == 2) ? bv : bsk;
        s16x8 bfrag[4][4];
        LOAD_BFRAG(bfrag, Wt, wc, lane);
        f32x4 acc[4];
#pragma unroll
        for (int nt = 0; nt < 4; nt++) acc[nt] = (f32x4){0.f, 0.f, 0.f, 0.f};
#pragma unroll
        for (int kk = 0; kk < 4; kk++) {
            s16x8 a = *(const s16x8*)&Asm[wr + (lane & 15)][kk * 32 + (lane >> 4) * 8];
#pragma unroll
            for (int nt = 0; nt < 4; nt++)
                acc[nt] = __builtin_amdgcn_mfma_f32_16x16x32_bf16(a, bfrag[nt][kk], acc[nt], 0, 0, 0);
        }
#pragma unroll
        for (int nt = 0; nt < 4; nt++) {
            int col = wc + nt * 16 + (lane & 15);
            float b = bias[col];
#pragma unroll
            for (int i = 0; i < 4; i++) {
                int row = row0 + wr + (lane >> 4) * 4 + i;
                if (row < Nn) {
                    float val = acc[nt][i] + b;
                    if (mat == 0)      qb[(size_t)row * 128 + col] = f2bf(val);
                    else if (mat == 1) kb[(size_t)row * 128 + col] = f2bf(val);
                    else if (mat == 2) vb[(size_t)row * 128 + col] = f2bf(val);
                    else               skb[(size_t)row * 128 + col] = val;
                }
            }
        }
    }
}

// ---------------- CSR build ----------------
__global__ void hist_dst(const int* __restrict__ eidx, int* __restrict__ cnt, int Ee) {
    int e = blockIdx.x * 256 + threadIdx.x;
    if (e < Ee) atomicAdd(&cnt[eidx[Ee + e]], 1);
}

__global__ __launch_bounds__(1024, 1) void scan_rowptr(const int* __restrict__ cnt,
                                                       int* __restrict__ rowptr, int Nn) {
    __shared__ int part[1024];
    int t = threadIdx.x;
    int chunk = (Nn + 1023) / 1024;
    int b = t * chunk;
    int e = b + chunk; if (e > Nn) e = Nn;
    int sum = 0;
    for (int i = b; i < e && i < Nn; i++) sum += cnt[i];
    part[t] = sum;
    __syncthreads();
    for (int off = 1; off < 1024; off <<= 1) {
        int v = (t >= off) ? part[t - off] : 0;
        __syncthreads();
        part[t] += v;
        __syncthreads();
    }
    int run = part[t] - sum;   // exclusive
    for (int i = b; i < e && i < Nn; i++) { rowptr[i] = run; run += cnt[i]; }
    if (t == 1023) rowptr[Nn] = part[1023];
}

// writes perm + packed {src,dst} materialized in perm (dst-sorted) order
__global__ void fill_perm2(const int* __restrict__ eidx, const int* __restrict__ rowptr,
                           int* __restrict__ cursor, int* __restrict__ perm,
                           int2* __restrict__ sd, int Ee) {
    int e = blockIdx.x * 256 + threadIdx.x;
    if (e >= Ee) return;
    int s = eidx[e];
    int d = eidx[Ee + e];
    int pos = atomicAdd(&cursor[d], 1);
    int i = rowptr[d] + pos;
    perm[i] = e;
    sd[i] = make_int2(s, d);
}

// ---------------- kernel 2: fused edge kernel (r6 structure + T14 prefetch pipeline) ----------------
// Each block owns a contiguous CHUNK of ~7 dst-sorted 64-edge tiles (XCD-swizzled
// chunk order). Per tile: stage(prefetched ea)->MFMA->Es->alpha(prefetched q/k)->PV.
// Prefetch for tile t+1 is issued in two stages (perm+sd at loop top; dependent
// ea + q/k after Es-write) so HBM/L2 gather latency hides under tile t's compute.
// Raw barriers (lgkmcnt only) keep the prefetch loads in flight across phases.
__global__ __launch_bounds__(512) void fused_edge(
    const float* __restrict__ ea, const short* __restrict__ Wt5,
    const short* __restrict__ qb, const short* __restrict__ kb,
    const short* __restrict__ vb,
    const int* __restrict__ perm, const int2* __restrict__ sd,
    float* __restrict__ outacc, float* __restrict__ denom, int Ee, int ntiles) {
    const short* Wt = Wt5 + 3 * 16384;  // We

    __shared__ short U[TILE_E][136];        // union: staged ea (bf16), then Es (bf16)
    __shared__ float Pls[TILE_E][HEADS];    // p = exp(alpha)
    __shared__ int Ss[TILE_E], Ds[TILE_E];

    int tid = threadIdx.x, wave = tid >> 6, lane = tid & 63;
    int wr = (wave >> 1) * 16, wc = (wave & 1) * 64;
    int aE = tid >> 3, aH = tid & 7;        // alpha role: (edge, head)

    // XCD-swizzled chunk mapping (NBLK multiple of 8 -> bijective)
    int chunk = (blockIdx.x & 7) * (NBLK / 8) + (blockIdx.x >> 3);
    int tpb = (ntiles + NBLK - 1) / NBLK;
    int t0 = chunk * tpb;
    int t1 = t0 + tpb; if (t1 > ntiles) t1 = ntiles;
    if (t0 >= ntiles) return;               // whole block exits: barrier-safe

    // ---- prologue: full prefetch of tile t0 ----
    float4 fl[4];
    int    pmreg[4];
    int2   sdreg;
    s16x8  pq0, pq1, pk0, pk1;
    {
        int e0 = t0 * TILE_E;
        int cnt = Ee - e0; if (cnt > TILE_E) cnt = TILE_E;
#pragma unroll
        for (int i = 0; i < 4; i++) {
            int f = tid + i * 512, r = f >> 5, c4 = f & 31;
            fl[i] = make_float4(0.f, 0.f, 0.f, 0.f);
            if (r < cnt) {
                int pe = perm[e0 + r];
                fl[i] = ((const float4*)ea)[(size_t)pe * 32 + c4];
            }
        }
        sdreg = make_int2(0, 0);
        if (aE < cnt) sdreg = sd[e0 + aE];
        const short* qp = &qb[(size_t)sdreg.y * 128 + aH * 16];
        const short* kp = &kb[(size_t)sdreg.x * 128 + aH * 16];
        pq0 = *(const s16x8*)qp; pq1 = *(const s16x8*)(qp + 8);
        pk0 = *(const s16x8*)kp; pk1 = *(const s16x8*)(kp + 8);
    }

    for (int t = t0; t < t1; t++) {
        int e0 = t * TILE_E;
        int cnt = Ee - e0; if (cnt > TILE_E) cnt = TILE_E;
        int tn = t + 1;
        bool havenext = (tn < t1);
        int e0n = tn * TILE_E;
        int cntn = Ee - e0n; if (cntn > TILE_E) cntn = TILE_E;

        // ---- stage: fl -> U (packed 8B stores); ids from alpha-role lane 0 ----
#pragma unroll
        for (int i = 0; i < 4; i++) {
            int f = tid + i * 512, r = f >> 5, c4 = f & 31;
            short4 pkd;
            pkd.x = f2bf(fl[i].x); pkd.y = f2bf(fl[i].y);
            pkd.z = f2bf(fl[i].z); pkd.w = f2bf(fl[i].w);
            *(short4*)&U[r][c4 * 4] = pkd;
        }
        if (aH == 0) { Ss[aE] = sdreg.x; Ds[aE] = sdreg.y; }

        // ---- prefetch stage 1 for t+1: perm + sd (L2-hot, feed stage 2) ----
        if (havenext) {
#pragma unroll
            for (int i = 0; i < 4; i++) {
                int f = tid + i * 512, r = f >> 5;
                pmreg[i] = (r < cntn) ? perm[e0n + r] : 0;
            }
            sdreg = make_int2(0, 0);
            if (aE < cntn) sdreg = sd[e0n + aE];
        }
        BAR();

        // ---- MFMA: e = ea_tile @ We ----
        f32x4 acc[4];
        {
            s16x8 bfrag[4][4];
            LOAD_BFRAG(bfrag, Wt, wc, lane);    // L1-resident 32KB
#pragma unroll
            for (int nt = 0; nt < 4; nt++) acc[nt] = (f32x4){0.f, 0.f, 0.f, 0.f};
#pragma unroll
            for (int kk = 0; kk < 4; kk++) {
                s16x8 a = *(const s16x8*)&U[wr + (lane & 15)][kk * 32 + (lane >> 4) * 8];
#pragma unroll
                for (int nt = 0; nt < 4; nt++)
                    acc[nt] = __builtin_amdgcn_mfma_f32_16x16x32_bf16(a, bfrag[nt][kk], acc[nt], 0, 0, 0);
            }
        }
        BAR();   // all U reads done

        // ---- Es (bf16) write over U ----
#pragma unroll
        for (int nt = 0; nt < 4; nt++) {
            int col = wc + nt * 16 + (lane & 15);
#pragma unroll
            for (int i = 0; i < 4; i++)
                U[wr + (lane >> 4) * 4 + i][col] = f2bf(acc[nt][i]);
        }

        // save tile-t alpha operands, then issue prefetch stage 2 for t+1
        s16x8 cq0 = pq0, cq1 = pq1, ck0 = pk0, ck1 = pk1;
        if (havenext) {
#pragma unroll
            for (int i = 0; i < 4; i++) {
                int f = tid + i * 512, r = f >> 5, c4 = f & 31;
                fl[i] = make_float4(0.f, 0.f, 0.f, 0.f);
                if (r < cntn)
                    fl[i] = ((const float4*)ea)[(size_t)pmreg[i] * 32 + c4];
            }
            const short* qp = &qb[(size_t)sdreg.y * 128 + aH * 16];
            const short* kp = &kb[(size_t)sdreg.x * 128 + aH * 16];
            pq0 = *(const s16x8*)qp; pq1 = *(const s16x8*)(qp + 8);
            pk0 = *(const s16x8*)kp; pk1 = *(const s16x8*)(kp + 8);
        }
        BAR();

        // ---- alpha + exp (one (edge,head) per thread; prefetched q/k) ----
        if (aE < cnt) {
            s16x8 ev0 = *(const s16x8*)&U[aE][aH * 16];
            s16x8 ev1 = *(const s16x8*)&U[aE][aH * 16 + 8];
            float a_val = 0.f;
#pragma unroll
            for (int c = 0; c < 8; c++) {
                a_val += bf2f(cq0[c]) * (bf2f(ck0[c]) + bf2f(ev0[c]));
                a_val += bf2f(cq1[c]) * (bf2f(ck1[c]) + bf2f(ev1[c]));
            }
            a_val *= 0.25f;                  // 1/sqrt(C), C=16
            // exp WITHOUT per-node max (cancels in p/sum p); clamp for inf-safety
            Pls[aE][aH] = __expf(fminf(a_val, 60.f));
        }
        BAR();

        // ---- PV: 8-edge group per wave, register run-aggregation, atomic flush ----
        {
            int base = wave * 8;
            int h = lane >> 3;               // head of this lane's channel pair
            float c0 = 0.f, c1 = 0.f, pd = 0.f;
            int curd = -1;
#pragma unroll
            for (int k = 0; k < 8; k++) {
                int eL = base + k;
                if (eL >= cnt) break;
                int d = Ds[eL];
                if (d != curd) {             // wave-uniform branch
                    if (curd >= 0) {
                        atomicAdd(&outacc[(size_t)curd * 128 + lane * 2],     c0);
                        atomicAdd(&outacc[(size_t)curd * 128 + lane * 2 + 1], c1);
                        if ((lane & 7) == 0) atomicAdd(&denom[(size_t)curd * HEADS + h], pd);
                    }
                    c0 = c1 = pd = 0.f;
                    curd = d;
                }
                float p = Pls[eL][h];                                   // LDS broadcast
                int src = Ss[eL];
                unsigned vv = *(const unsigned*)&vb[(size_t)src * 128 + lane * 2];
                unsigned ee = *(const unsigned*)&U[eL][lane * 2];
                c0 += p * (bf2f((short)(vv & 0xffff)) + bf2f((short)(ee & 0xffff)));
                c1 += p * (bf2f((short)(vv >> 16))    + bf2f((short)(ee >> 16)));
                if ((lane & 7) == 0) pd += p;
            }
            if (curd >= 0) {
                atomicAdd(&outacc[(size_t)curd * 128 + lane * 2],     c0);
                atomicAdd(&outacc[(size_t)curd * 128 + lane * 2 + 1], c1);
                if ((lane & 7) == 0) atomicAdd(&denom[(size_t)curd * HEADS + h], pd);
            }
        }
        BAR();   // U/Pls/Ss/Ds free for next tile's staging
    }
}

// ---------------- kernel 3: finalize out = outacc/(denom+eps) + skip ----------------
__global__ void finalize(const float* __restrict__ outacc, const float* __restrict__ denom,
                         const float* __restrict__ skb, float* __restrict__ out, int total4) {
    int idx = blockIdx.x * 256 + threadIdx.x;
    if (idx >= total4) return;                 // total4 = N*32 (float4 units)
    int n = idx >> 5, q4 = idx & 31;
    int h = q4 >> 2;
    float inv = 1.f / (denom[(size_t)n * HEADS + h] + 1e-16f);
    float4 a = ((const float4*)outacc)[idx];
    float4 sk = ((const float4*)skb)[idx];
    float4 r = make_float4(a.x * inv + sk.x, a.y * inv + sk.y,
                           a.z * inv + sk.z, a.w * inv + sk.w);
    ((float4*)out)[idx] = r;
}

// ---------------- launch ----------------
extern "C" void kernel_launch(void* const* d_in, const int* in_sizes, int n_in,
                              void* d_out, int out_size, void* d_ws, size_t ws_size,
                              hipStream_t stream) {
    const float* x   = (const float*)d_in[0];
    const float* ea  = (const float*)d_in[1];
    const float* Wq  = (const float*)d_in[2];
    const float* bq  = (const float*)d_in[3];
    const float* Wk  = (const float*)d_in[4];
    const float* bk  = (const float*)d_in[5];
    const float* Wv  = (const float*)d_in[6];
    const float* bv  = (const float*)d_in[7];
    const float* We  = (const float*)d_in[8];
    const float* Wsk = (const float*)d_in[9];
    const float* bsk = (const float*)d_in[10];
    const int*   eidx = (const int*)d_in[11];

    int Nn = in_sizes[0] / 128;   // 50000
    int Ee = in_sizes[1] / 128;   // 800000
    float* out = (float*)d_out;

    // ws layout
    size_t need = 0;
    size_t off_qb  = need; need += (size_t)Nn * 128 * 2;   // qb bf16
    size_t off_kb  = need; need += (size_t)Nn * 128 * 2;   // kb bf16
    size_t off_vb  = need; need += (size_t)Nn * 128 * 2;   // vb bf16
    size_t off_skb = need; need += (size_t)Nn * 128 * 4;   // skip f32
    size_t off_oa  = need; need += (size_t)Nn * 128 * 4;   // outacc f32
    size_t off_dn  = need; need += (size_t)Nn * HEADS * 4; // denom f32
    size_t off_perm= need; need += (size_t)Ee * 4;         // perm
    size_t off_sd  = need; need += (size_t)Ee * 8;         // {src,dst} packed (perm order)
    size_t off_rp  = need; need += (size_t)(Nn + 1) * 4;   // rowptr
    size_t off_cnt = need; need += (size_t)Nn * 4;         // counts
    size_t off_cur = need; need += (size_t)Nn * 4;         // cursors
    size_t off_wt  = need; need += 5 * 16384 * 2;          // Wt5
    (void)need;

    char* ws = (char*)d_ws;
    short* qb    = (short*)(ws + off_qb);
    short* kb    = (short*)(ws + off_kb);
    short* vb    = (short*)(ws + off_vb);
    float* skb   = (float*)(ws + off_skb);
    float* outacc= (float*)(ws + off_oa);
    float* denom = (float*)(ws + off_dn);
    int*   perm  = (int*)(ws + off_perm);
    int2*  sd    = (int2*)(ws + off_sd);
    int*   rowptr= (int*)(ws + off_rp);
    int*   cnt   = (int*)(ws + off_cnt);
    int*   cursor= (int*)(ws + off_cur);
    short* Wt5   = (short*)(ws + off_wt);

    hipMemsetAsync(cnt, 0, (size_t)Nn * 4, stream);
    hipMemsetAsync(cursor, 0, (size_t)Nn * 4, stream);
    hipMemsetAsync(outacc, 0, (size_t)Nn * 128 * 4, stream);
    hipMemsetAsync(denom, 0, (size_t)Nn * HEADS * 4, stream);

    int ntiles = (Ee + TILE_E - 1) / TILE_E;

    prep_w<<<(5 * 16384 + 255) / 256, 256, 0, stream>>>(Wq, Wk, Wv, We, Wsk, Wt5);
    hist_dst<<<(Ee + 255) / 256, 256, 0, stream>>>(eidx, cnt, Ee);
    scan_rowptr<<<1, 1024, 0, stream>>>(cnt, rowptr, Nn);
    fill_perm2<<<(Ee + 255) / 256, 256, 0, stream>>>(eidx, rowptr, cursor, perm, sd, Ee);
    node_proj<<<(Nn + TILE_N - 1) / TILE_N, 512, 0, stream>>>(
        x, Wt5, bq, bk, bv, bsk, qb, kb, vb, skb, Nn);
    fused_edge<<<NBLK, 512, 0, stream>>>(
        ea, Wt5, qb, kb, vb, perm, sd, outacc, denom, Ee, ntiles);
    finalize<<<(Nn * 32 + 255) / 256, 256, 0, stream>>>(
        outacc, denom, skb, out, Nn * 32);
}

// Round 10
// 639.876 us; speedup vs baseline: 1.2734x; 1.2734x over previous
//
#include <hip/hip_runtime.h>

// ---------------- types & helpers ----------------
typedef __attribute__((ext_vector_type(4))) float  f32x4;
typedef __attribute__((ext_vector_type(8))) short  s16x8;

__device__ __forceinline__ short f2bf(float f) {
    unsigned u = __builtin_bit_cast(unsigned, f);
    u += 0x7FFFu + ((u >> 16) & 1u);            // round-to-nearest-even
    return (short)(u >> 16);
}
__device__ __forceinline__ float bf2f(short s) {
    unsigned u = ((unsigned)(unsigned short)s) << 16;
    return __builtin_bit_cast(float, u);
}

#define DEPTH 128   // D == H*C == 128
#define HEADS 8
#define TILE_N 64   // node_proj tile
#define TILE_E 64   // fused_edge tile

// ---------------- kernel 0: W -> bf16, transposed (Wt[c][k]) ----------------
// order: 0=Wq 1=Wk 2=Wv 3=We 4=Wskip
__global__ void prep_w(const float* __restrict__ Wq, const float* __restrict__ Wk,
                       const float* __restrict__ Wv, const float* __restrict__ We,
                       const float* __restrict__ Wsk, short* __restrict__ Wt5) {
    int idx = blockIdx.x * 256 + threadIdx.x;
    if (idx >= 5 * DEPTH * DEPTH) return;
    int mat = idx >> 14;
    int rem = idx & 16383;
    int k = rem >> 7, c = rem & 127;
    const float* W = (mat == 0) ? Wq : (mat == 1) ? Wk : (mat == 2) ? Wv : (mat == 3) ? We : Wsk;
    Wt5[mat * 16384 + c * 128 + k] = f2bf(W[k * 128 + c]);
}

// ---------------- shared GEMM pieces ----------------
#define LOAD_BFRAG(bfrag, Wt, wc, lane)                                         \
    _Pragma("unroll") for (int nt_ = 0; nt_ < 4; nt_++)                         \
    _Pragma("unroll") for (int kk_ = 0; kk_ < 4; kk_++) {                       \
        int col_ = (wc) + nt_ * 16 + ((lane) & 15);                             \
        int kidx_ = kk_ * 32 + ((lane) >> 4) * 8;                               \
        bfrag[nt_][kk_] = *(const s16x8*)&(Wt)[col_ * 128 + kidx_];             \
    }

// ---------------- kernel 1: node projections (single pass, all 4 mats) ----------------
__global__ __launch_bounds__(512, 1) void node_proj(
    const float* __restrict__ x, const short* __restrict__ Wt5,
    const float* __restrict__ bq, const float* __restrict__ bk,
    const float* __restrict__ bv, const float* __restrict__ bsk,
    short* __restrict__ qb, short* __restrict__ kb, short* __restrict__ vb,
    float* __restrict__ skb, int Nn) {
    __shared__ short Asm[TILE_N][136];
    int tid = threadIdx.x, wave = tid >> 6, lane = tid & 63;
    int row0 = blockIdx.x * TILE_N;

    for (int i_ = 0; i_ < 4; i_++) {
        int f_ = tid + i_ * 512;
        int r_ = f_ >> 5, c4_ = f_ & 31;
        int gr_ = row0 + r_;
        float4 v_ = (gr_ < Nn) ? ((const float4*)x)[(size_t)gr_ * 32 + c4_]
                               : make_float4(0.f, 0.f, 0.f, 0.f);
        short* d_ = &Asm[r_][c4_ * 4];
        d_[0] = f2bf(v_.x); d_[1] = f2bf(v_.y); d_[2] = f2bf(v_.z); d_[3] = f2bf(v_.w);
    }
    __syncthreads();

    int wr = (wave >> 1) * 16, wc = (wave & 1) * 64;

    for (int mat = 0; mat < 4; mat++) {
        const short* Wt = Wt5 + ((mat < 3) ? mat : 4) * 16384;
        const float* bias = (mat == 0) ? bq : (mat == 1) ? bk : (mat == 2) ? bv : bsk;
        s16x8 bfrag[4][4];
        LOAD_BFRAG(bfrag, Wt, wc, lane);
        f32x4 acc[4];
#pragma unroll
        for (int nt = 0; nt < 4; nt++) acc[nt] = (f32x4){0.f, 0.f, 0.f, 0.f};
#pragma unroll
        for (int kk = 0; kk < 4; kk++) {
            s16x8 a = *(const s16x8*)&Asm[wr + (lane & 15)][kk * 32 + (lane >> 4) * 8];
#pragma unroll
            for (int nt = 0; nt < 4; nt++)
                acc[nt] = __builtin_amdgcn_mfma_f32_16x16x32_bf16(a, bfrag[nt][kk], acc[nt], 0, 0, 0);
        }
#pragma unroll
        for (int nt = 0; nt < 4; nt++) {
            int col = wc + nt * 16 + (lane & 15);
            float b = bias[col];
#pragma unroll
            for (int i = 0; i < 4; i++) {
                int row = row0 + wr + (lane >> 4) * 4 + i;
                if (row < Nn) {
                    float val = acc[nt][i] + b;
                    if (mat == 0)      qb[(size_t)row * 128 + col] = f2bf(val);
                    else if (mat == 1) kb[(size_t)row * 128 + col] = f2bf(val);
                    else if (mat == 2) vb[(size_t)row * 128 + col] = f2bf(val);
                    else               skb[(size_t)row * 128 + col] = val;
                }
            }
        }
    }
}

// ---------------- CSR build ----------------
__global__ void hist_dst(const int* __restrict__ eidx, int* __restrict__ cnt, int Ee) {
    int e = blockIdx.x * 256 + threadIdx.x;
    if (e < Ee) atomicAdd(&cnt[eidx[Ee + e]], 1);
}

__global__ __launch_bounds__(1024, 1) void scan_rowptr(const int* __restrict__ cnt,
                                                       int* __restrict__ rowptr, int Nn) {
    __shared__ int part[1024];
    int t = threadIdx.x;
    int chunk = (Nn + 1023) / 1024;
    int b = t * chunk;
    int e = b + chunk; if (e > Nn) e = Nn;
    int sum = 0;
    for (int i = b; i < e && i < Nn; i++) sum += cnt[i];
    part[t] = sum;
    __syncthreads();
    for (int off = 1; off < 1024; off <<= 1) {
        int v = (t >= off) ? part[t - off] : 0;
        __syncthreads();
        part[t] += v;
        __syncthreads();
    }
    int run = part[t] - sum;   // exclusive
    for (int i = b; i < e && i < Nn; i++) { rowptr[i] = run; run += cnt[i]; }
    if (t == 1023) rowptr[Nn] = part[1023];
}

// writes perm + packed {src,dst} materialized in perm (dst-sorted) order
__global__ void fill_perm2(const int* __restrict__ eidx, const int* __restrict__ rowptr,
                           int* __restrict__ cursor, int* __restrict__ perm,
                           int2* __restrict__ sd, int Ee) {
    int e = blockIdx.x * 256 + threadIdx.x;
    if (e >= Ee) return;
    int s = eidx[e];
    int d = eidx[Ee + e];
    int pos = atomicAdd(&cursor[d], 1);
    int i = rowptr[d] + pos;
    perm[i] = e;
    sd[i] = make_int2(s, d);
}

// ---------------- kernel 2: fused edge kernel — zero-stage direct-A MFMA ----------------
// 256 threads = 4 waves; one 64-edge dst-sorted tile per block. Wave w owns rows
// w*16..w*16+15 and BOTH column halves. Each lane loads its MFMA A-fragments
// DIRECTLY from global ea (8 x float4 in flight, no LDS staging, no stage
// barrier) and converts f32->bf16 in-register. LDS holds only the e-projection
// (Es bf16), Pls, and the src/dst ids. Then r6's proven alpha + PV phases.
__global__ __launch_bounds__(256) void fused_edge(
    const float* __restrict__ ea, const short* __restrict__ Wt5,
    const short* __restrict__ qb, const short* __restrict__ kb,
    const short* __restrict__ vb,
    const int* __restrict__ perm, const int2* __restrict__ sd,
    float* __restrict__ outacc, float* __restrict__ denom, int Ee) {
    const short* Wt = Wt5 + 3 * 16384;  // We

    __shared__ short Es[TILE_E][136];       // 17.4 KB: e = ea@We in bf16
    __shared__ float Pls[TILE_E][HEADS];    // 2 KB: p = exp(alpha)
    __shared__ int Ss[TILE_E], Ds[TILE_E];  // 0.5 KB

    int tid = threadIdx.x, wave = tid >> 6, lane = tid & 63;
    int e0 = blockIdx.x * TILE_E;
    int cnt = Ee - e0; if (cnt > TILE_E) cnt = TILE_E;

    // ---- ids (one wave's worth of int2 loads) ----
    if (tid < TILE_E) {
        int2 v = (tid < cnt) ? sd[e0 + tid] : make_int2(0, -1);
        Ss[tid] = v.x; Ds[tid] = v.y;
    }

    // ---- direct A-fragment global loads: row = wave*16 + (lane&15), part = lane>>4 ----
    int row = wave * 16 + (lane & 15);
    int pe = perm[e0 + ((row < cnt) ? row : 0)];      // 16 distinct values/wave, L2
    const float* arow = ea + (size_t)pe * 128 + (lane >> 4) * 8;
    float4 fa[8];
#pragma unroll
    for (int kk = 0; kk < 4; kk++) {
        fa[2 * kk]     = *(const float4*)(arow + kk * 32);
        fa[2 * kk + 1] = *(const float4*)(arow + kk * 32 + 4);
    }
    s16x8 afr[4];
#pragma unroll
    for (int kk = 0; kk < 4; kk++) {
        s16x8 t;
        t[0] = f2bf(fa[2 * kk].x);     t[1] = f2bf(fa[2 * kk].y);
        t[2] = f2bf(fa[2 * kk].z);     t[3] = f2bf(fa[2 * kk].w);
        t[4] = f2bf(fa[2 * kk + 1].x); t[5] = f2bf(fa[2 * kk + 1].y);
        t[6] = f2bf(fa[2 * kk + 1].z); t[7] = f2bf(fa[2 * kk + 1].w);
        afr[kk] = t;
    }

    // ---- MFMA: e = ea_tile @ We, both column halves (A loaded once) ----
    f32x4 acc[2][4];
#pragma unroll
    for (int half = 0; half < 2; half++) {
        int wc = half * 64;
        s16x8 bfrag[4][4];
        LOAD_BFRAG(bfrag, Wt, wc, lane);    // L1-resident 32KB
#pragma unroll
        for (int nt = 0; nt < 4; nt++) acc[half][nt] = (f32x4){0.f, 0.f, 0.f, 0.f};
#pragma unroll
        for (int kk = 0; kk < 4; kk++)
#pragma unroll
            for (int nt = 0; nt < 4; nt++)
                acc[half][nt] = __builtin_amdgcn_mfma_f32_16x16x32_bf16(
                    afr[kk], bfrag[nt][kk], acc[half][nt], 0, 0, 0);
    }

    // ---- write Es (bf16) ----
#pragma unroll
    for (int half = 0; half < 2; half++)
#pragma unroll
    for (int nt = 0; nt < 4; nt++) {
        int col = half * 64 + nt * 16 + (lane & 15);
#pragma unroll
        for (int i = 0; i < 4; i++)
            Es[wave * 16 + (lane >> 4) * 4 + i][col] = f2bf(acc[half][nt][i]);
    }
    __syncthreads();

    // ---- alpha + exp: one (edge, head) per thread, 2 iterations ----
#pragma unroll
    for (int it = 0; it < 2; it++) {
        int t = it * 256 + tid;
        int eL = t >> 3, hh = t & 7;
        if (eL < cnt) {
            int src = Ss[eL], dst = Ds[eL];
            const short* qp = &qb[(size_t)dst * 128 + hh * 16];
            const short* kp = &kb[(size_t)src * 128 + hh * 16];
            s16x8 q0 = *(const s16x8*)qp, q1 = *(const s16x8*)(qp + 8);
            s16x8 k0 = *(const s16x8*)kp, k1 = *(const s16x8*)(kp + 8);
            s16x8 ev0 = *(const s16x8*)&Es[eL][hh * 16];
            s16x8 ev1 = *(const s16x8*)&Es[eL][hh * 16 + 8];
            float a_val = 0.f;
#pragma unroll
            for (int c = 0; c < 8; c++) {
                a_val += bf2f(q0[c]) * (bf2f(k0[c]) + bf2f(ev0[c]));
                a_val += bf2f(q1[c]) * (bf2f(k1[c]) + bf2f(ev1[c]));
            }
            a_val *= 0.25f;                  // 1/sqrt(C), C=16
            // exp WITHOUT per-node max (cancels in p/sum p); clamp for inf-safety
            Pls[eL][hh] = __expf(fminf(a_val, 60.f));
        }
    }
    __syncthreads();

    // ---- PV: wave = 16-edge group, register run-aggregation, atomic flush ----
    {
        int base = wave * 16;
        int h = lane >> 3;                   // head of this lane's channel pair
        float c0 = 0.f, c1 = 0.f, pd = 0.f;
        int curd = -1;
#pragma unroll
        for (int k = 0; k < 16; k++) {
            int eL = base + k;
            if (eL >= cnt) break;
            int d = Ds[eL];
            if (d != curd) {                 // wave-uniform branch
                if (curd >= 0) {
                    atomicAdd(&outacc[(size_t)curd * 128 + lane * 2],     c0);
                    atomicAdd(&outacc[(size_t)curd * 128 + lane * 2 + 1], c1);
                    if ((lane & 7) == 0) atomicAdd(&denom[(size_t)curd * HEADS + h], pd);
                }
                c0 = c1 = pd = 0.f;
                curd = d;
            }
            float p = Pls[eL][h];                                   // LDS broadcast
            int src = Ss[eL];
            unsigned vv = *(const unsigned*)&vb[(size_t)src * 128 + lane * 2];
            unsigned ee = *(const unsigned*)&Es[eL][lane * 2];
            c0 += p * (bf2f((short)(vv & 0xffff)) + bf2f((short)(ee & 0xffff)));
            c1 += p * (bf2f((short)(vv >> 16))    + bf2f((short)(ee >> 16)));
            if ((lane & 7) == 0) pd += p;
        }
        if (curd >= 0) {
            atomicAdd(&outacc[(size_t)curd * 128 + lane * 2],     c0);
            atomicAdd(&outacc[(size_t)curd * 128 + lane * 2 + 1], c1);
            if ((lane & 7) == 0) atomicAdd(&denom[(size_t)curd * HEADS + h], pd);
        }
    }
}

// ---------------- kernel 3: finalize out = outacc/(denom+eps) + skip ----------------
__global__ void finalize(const float* __restrict__ outacc, const float* __restrict__ denom,
                         const float* __restrict__ skb, float* __restrict__ out, int total4) {
    int idx = blockIdx.x * 256 + threadIdx.x;
    if (idx >= total4) return;                 // total4 = N*32 (float4 units)
    int n = idx >> 5, q4 = idx & 31;
    int h = q4 >> 2;
    float inv = 1.f / (denom[(size_t)n * HEADS + h] + 1e-16f);
    float4 a = ((const float4*)outacc)[idx];
    float4 sk = ((const float4*)skb)[idx];
    float4 r = make_float4(a.x * inv + sk.x, a.y * inv + sk.y,
                           a.z * inv + sk.z, a.w * inv + sk.w);
    ((float4*)out)[idx] = r;
}

// ---------------- launch ----------------
extern "C" void kernel_launch(void* const* d_in, const int* in_sizes, int n_in,
                              void* d_out, int out_size, void* d_ws, size_t ws_size,
                              hipStream_t stream) {
    const float* x   = (const float*)d_in[0];
    const float* ea  = (const float*)d_in[1];
    const float* Wq  = (const float*)d_in[2];
    const float* bq  = (const float*)d_in[3];
    const float* Wk  = (const float*)d_in[4];
    const float* bk  = (const float*)d_in[5];
    const float* Wv  = (const float*)d_in[6];
    const float* bv  = (const float*)d_in[7];
    const float* We  = (const float*)d_in[8];
    const float* Wsk = (const float*)d_in[9];
    const float* bsk = (const float*)d_in[10];
    const int*   eidx = (const int*)d_in[11];

    int Nn = in_sizes[0] / 128;   // 50000
    int Ee = in_sizes[1] / 128;   // 800000
    float* out = (float*)d_out;

    // ws layout
    size_t need = 0;
    size_t off_qb  = need; need += (size_t)Nn * 128 * 2;   // qb bf16
    size_t off_kb  = need; need += (size_t)Nn * 128 * 2;   // kb bf16
    size_t off_vb  = need; need += (size_t)Nn * 128 * 2;   // vb bf16
    size_t off_skb = need; need += (size_t)Nn * 128 * 4;   // skip f32
    size_t off_oa  = need; need += (size_t)Nn * 128 * 4;   // outacc f32
    size_t off_dn  = need; need += (size_t)Nn * HEADS * 4; // denom f32
    size_t off_perm= need; need += (size_t)Ee * 4;         // perm
    size_t off_sd  = need; need += (size_t)Ee * 8;         // {src,dst} packed (perm order)
    size_t off_rp  = need; need += (size_t)(Nn + 1) * 4;   // rowptr
    size_t off_cnt = need; need += (size_t)Nn * 4;         // counts
    size_t off_cur = need; need += (size_t)Nn * 4;         // cursors
    size_t off_wt  = need; need += 5 * 16384 * 2;          // Wt5
    (void)need;

    char* ws = (char*)d_ws;
    short* qb    = (short*)(ws + off_qb);
    short* kb    = (short*)(ws + off_kb);
    short* vb    = (short*)(ws + off_vb);
    float* skb   = (float*)(ws + off_skb);
    float* outacc= (float*)(ws + off_oa);
    float* denom = (float*)(ws + off_dn);
    int*   perm  = (int*)(ws + off_perm);
    int2*  sd    = (int2*)(ws + off_sd);
    int*   rowptr= (int*)(ws + off_rp);
    int*   cnt   = (int*)(ws + off_cnt);
    int*   cursor= (int*)(ws + off_cur);
    short* Wt5   = (short*)(ws + off_wt);

    hipMemsetAsync(cnt, 0, (size_t)Nn * 4, stream);
    hipMemsetAsync(cursor, 0, (size_t)Nn * 4, stream);
    hipMemsetAsync(outacc, 0, (size_t)Nn * 128 * 4, stream);
    hipMemsetAsync(denom, 0, (size_t)Nn * HEADS * 4, stream);

    int ntiles = (Ee + TILE_E - 1) / TILE_E;

    prep_w<<<(5 * 16384 + 255) / 256, 256, 0, stream>>>(Wq, Wk, Wv, We, Wsk, Wt5);
    hist_dst<<<(Ee + 255) / 256, 256, 0, stream>>>(eidx, cnt, Ee);
    scan_rowptr<<<1, 1024, 0, stream>>>(cnt, rowptr, Nn);
    fill_perm2<<<(Ee + 255) / 256, 256, 0, stream>>>(eidx, rowptr, cursor, perm, sd, Ee);
    node_proj<<<(Nn + TILE_N - 1) / TILE_N, 512, 0, stream>>>(
        x, Wt5, bq, bk, bv, bsk, qb, kb, vb, skb, Nn);
    fused_edge<<<ntiles, 256, 0, stream>>>(
        ea, Wt5, qb, kb, vb, perm, sd, outacc, denom, Ee);
    finalize<<<(Nn * 32 + 255) / 256, 256, 0, stream>>>(
        outacc, denom, skb, out, Nn * 32);
}

// Round 11
// 554.554 us; speedup vs baseline: 1.4693x; 1.1539x over previous
//
#include <hip/hip_runtime.h>

// ---------------- types & helpers ----------------
typedef __attribute__((ext_vector_type(4))) float  f32x4;
typedef __attribute__((ext_vector_type(8))) short  s16x8;

__device__ __forceinline__ short f2bf(float f) {
    unsigned u = __builtin_bit_cast(unsigned, f);
    u += 0x7FFFu + ((u >> 16) & 1u);            // round-to-nearest-even
    return (short)(u >> 16);
}
__device__ __forceinline__ float bf2f(short s) {
    unsigned u = ((unsigned)(unsigned short)s) << 16;
    return __builtin_bit_cast(float, u);
}

#define DEPTH 128   // D == H*C == 128
#define HEADS 8
#define TILE_M 64

// ---------------- kernel 0: W -> bf16, transposed (Wt[c][k]) ----------------
// order: 0=Wq 1=Wk 2=Wv 3=We 4=Wskip
__global__ void prep_w(const float* __restrict__ Wq, const float* __restrict__ Wk,
                       const float* __restrict__ Wv, const float* __restrict__ We,
                       const float* __restrict__ Wsk, short* __restrict__ Wt5) {
    int idx = blockIdx.x * 256 + threadIdx.x;
    if (idx >= 5 * DEPTH * DEPTH) return;
    int mat = idx >> 14;
    int rem = idx & 16383;
    int k = rem >> 7, c = rem & 127;
    const float* W = (mat == 0) ? Wq : (mat == 1) ? Wk : (mat == 2) ? Wv : (mat == 3) ? We : Wsk;
    Wt5[mat * 16384 + c * 128 + k] = f2bf(W[k * 128 + c]);
}

// ---------------- shared GEMM pieces ----------------
#define LOAD_BFRAG(bfrag, Wt, wc, lane)                                         \
    _Pragma("unroll") for (int nt_ = 0; nt_ < 4; nt_++)                         \
    _Pragma("unroll") for (int kk_ = 0; kk_ < 4; kk_++) {                       \
        int col_ = (wc) + nt_ * 16 + ((lane) & 15);                             \
        int kidx_ = kk_ * 32 + ((lane) >> 4) * 8;                               \
        bfrag[nt_][kk_] = *(const s16x8*)&(Wt)[col_ * 128 + kidx_];             \
    }

// ---------------- kernel 1: node projections (single pass, all 4 mats) ----------------
__global__ __launch_bounds__(512, 1) void node_proj(
    const float* __restrict__ x, const short* __restrict__ Wt5,
    const float* __restrict__ bq, const float* __restrict__ bk,
    const float* __restrict__ bv, const float* __restrict__ bsk,
    short* __restrict__ qb, short* __restrict__ kb, short* __restrict__ vb,
    float* __restrict__ skb, int Nn) {
    __shared__ short Asm[TILE_M][136];
    int tid = threadIdx.x, wave = tid >> 6, lane = tid & 63;
    int row0 = blockIdx.x * TILE_M;

    for (int i_ = 0; i_ < 4; i_++) {
        int f_ = tid + i_ * 512;
        int r_ = f_ >> 5, c4_ = f_ & 31;
        int gr_ = row0 + r_;
        float4 v_ = (gr_ < Nn) ? ((const float4*)x)[(size_t)gr_ * 32 + c4_]
                               : make_float4(0.f, 0.f, 0.f, 0.f);
        short* d_ = &Asm[r_][c4_ * 4];
        d_[0] = f2bf(v_.x); d_[1] = f2bf(v_.y); d_[2] = f2bf(v_.z); d_[3] = f2bf(v_.w);
    }
    __syncthreads();

    int wr = (wave >> 1) * 16, wc = (wave & 1) * 64;

    for (int mat = 0; mat < 4; mat++) {
        const short* Wt = Wt5 + ((mat < 3) ? mat : 4) * 16384;
        const float* bias = (mat == 0) ? bq : (mat == 1) ? bk : (mat == 2) ? bv : bsk;
        s16x8 bfrag[4][4];
        LOAD_BFRAG(bfrag, Wt, wc, lane);
        f32x4 acc[4];
#pragma unroll
        for (int nt = 0; nt < 4; nt++) acc[nt] = (f32x4){0.f, 0.f, 0.f, 0.f};
#pragma unroll
        for (int kk = 0; kk < 4; kk++) {
            s16x8 a = *(const s16x8*)&Asm[wr + (lane & 15)][kk * 32 + (lane >> 4) * 8];
#pragma unroll
            for (int nt = 0; nt < 4; nt++)
                acc[nt] = __builtin_amdgcn_mfma_f32_16x16x32_bf16(a, bfrag[nt][kk], acc[nt], 0, 0, 0);
        }
#pragma unroll
        for (int nt = 0; nt < 4; nt++) {
            int col = wc + nt * 16 + (lane & 15);
            float b = bias[col];
#pragma unroll
            for (int i = 0; i < 4; i++) {
                int row = row0 + wr + (lane >> 4) * 4 + i;
                if (row < Nn) {
                    float val = acc[nt][i] + b;
                    if (mat == 0)      qb[(size_t)row * 128 + col] = f2bf(val);
                    else if (mat == 1) kb[(size_t)row * 128 + col] = f2bf(val);
                    else if (mat == 2) vb[(size_t)row * 128 + col] = f2bf(val);
                    else               skb[(size_t)row * 128 + col] = val;
                }
            }
        }
    }
}

// ---------------- CSR build ----------------
__global__ void hist_dst(const int* __restrict__ eidx, int* __restrict__ cnt, int Ee) {
    int e = blockIdx.x * 256 + threadIdx.x;
    if (e < Ee) atomicAdd(&cnt[eidx[Ee + e]], 1);
}

__global__ __launch_bounds__(1024, 1) void scan_rowptr(const int* __restrict__ cnt,
                                                       int* __restrict__ rowptr, int Nn) {
    __shared__ int part[1024];
    int t = threadIdx.x;
    int chunk = (Nn + 1023) / 1024;
    int b = t * chunk;
    int e = b + chunk; if (e > Nn) e = Nn;
    int sum = 0;
    for (int i = b; i < e && i < Nn; i++) sum += cnt[i];
    part[t] = sum;
    __syncthreads();
    for (int off = 1; off < 1024; off <<= 1) {
        int v = (t >= off) ? part[t - off] : 0;
        __syncthreads();
        part[t] += v;
        __syncthreads();
    }
    int run = part[t] - sum;   // exclusive
    for (int i = b; i < e && i < Nn; i++) { rowptr[i] = run; run += cnt[i]; }
    if (t == 1023) rowptr[Nn] = part[1023];
}

// writes perm + srcs/dsts materialized in perm (dst-sorted) order
__global__ void fill_perm2(const int* __restrict__ eidx, const int* __restrict__ rowptr,
                           int* __restrict__ cursor, int* __restrict__ perm,
                           int* __restrict__ srcs, int* __restrict__ dsts, int Ee) {
    int e = blockIdx.x * 256 + threadIdx.x;
    if (e >= Ee) return;
    int s = eidx[e];
    int d = eidx[Ee + e];
    int pos = atomicAdd(&cursor[d], 1);
    int i = rowptr[d] + pos;
    perm[i] = e; srcs[i] = s; dsts[i] = d;
}

// ---------------- kernel 2: fused edge kernel (r6 structure + load-exposure fixes) ----------------
// One 64-edge dst-sorted tile per block, 512 threads.
//   phase 0: BURST-stage ea (4 float4 issued before any LDS write)
//   phase 1: MFMA e = ea@We -> Es bf16 (separate buffer, r6's 3-barrier layout)
//   phase 2: alpha + exp, one (edge,head) per thread
//   phase 3: PV with PRELOADED vb rows (8 independent L3 loads in flight/lane),
//            register run-aggregation, global atomicAdd flush at dst changes.
__global__ __launch_bounds__(512) void fused_edge(
    const float* __restrict__ ea, const short* __restrict__ Wt5,
    const short* __restrict__ qb, const short* __restrict__ kb,
    const short* __restrict__ vb,
    const int* __restrict__ perm, const int* __restrict__ srcs,
    const int* __restrict__ dsts,
    float* __restrict__ outacc, float* __restrict__ denom, int Ee) {
    const short* Wt = Wt5 + 3 * 16384;  // We

    __shared__ short Asm[TILE_M][136];      // 17.4 KB staged ea (bf16)
    __shared__ short Es[TILE_M][136];       // 17.4 KB e-projection (bf16)
    __shared__ float Pls[TILE_M][HEADS];    // 2 KB p = exp(alpha)
    __shared__ int Ss[TILE_M], Ds[TILE_M];

    int tid = threadIdx.x, wave = tid >> 6, lane = tid & 63;
    int e0 = blockIdx.x * TILE_M;
    int cnt = Ee - e0; if (cnt > TILE_M) cnt = TILE_M;

    // ---- phase 0: ids + BURST-staged ea rows ----
    if (tid < TILE_M) {
        Ss[tid] = (tid < cnt) ? srcs[e0 + tid] : 0;
        Ds[tid] = (tid < cnt) ? dsts[e0 + tid] : -1;
    }
    {
        float4 fl[4];
#pragma unroll
        for (int i_ = 0; i_ < 4; i_++) {
            int f_ = tid + i_ * 512;
            int r_ = f_ >> 5, c4_ = f_ & 31;
            fl[i_] = make_float4(0.f, 0.f, 0.f, 0.f);
            if (r_ < cnt) {
                int pe = perm[e0 + r_];      // redundant across 32 lanes, L1-hot
                fl[i_] = ((const float4*)ea)[(size_t)pe * 32 + c4_];
            }
        }
#pragma unroll
        for (int i_ = 0; i_ < 4; i_++) {
            int f_ = tid + i_ * 512;
            int r_ = f_ >> 5, c4_ = f_ & 31;
            short4 pkd;
            pkd.x = f2bf(fl[i_].x); pkd.y = f2bf(fl[i_].y);
            pkd.z = f2bf(fl[i_].z); pkd.w = f2bf(fl[i_].w);
            *(short4*)&Asm[r_][c4_ * 4] = pkd;
        }
    }
    __syncthreads();

    // ---- phase 1: MFMA e = ea_tile @ We -> Es (bf16) ----
    int wr = (wave >> 1) * 16, wc = (wave & 1) * 64;
    {
        s16x8 bfrag[4][4];
        LOAD_BFRAG(bfrag, Wt, wc, lane);    // L1-resident 32KB
        f32x4 acc[4];
#pragma unroll
        for (int nt = 0; nt < 4; nt++) acc[nt] = (f32x4){0.f, 0.f, 0.f, 0.f};
#pragma unroll
        for (int kk = 0; kk < 4; kk++) {
            s16x8 a = *(const s16x8*)&Asm[wr + (lane & 15)][kk * 32 + (lane >> 4) * 8];
#pragma unroll
            for (int nt = 0; nt < 4; nt++)
                acc[nt] = __builtin_amdgcn_mfma_f32_16x16x32_bf16(a, bfrag[nt][kk], acc[nt], 0, 0, 0);
        }
#pragma unroll
        for (int nt = 0; nt < 4; nt++) {
            int col = wc + nt * 16 + (lane & 15);
#pragma unroll
            for (int i = 0; i < 4; i++)
                Es[wr + (lane >> 4) * 4 + i][col] = f2bf(acc[nt][i]);
        }
    }
    __syncthreads();

    // ---- phase 2: alpha + exp (one (edge, head) per thread; no reductions) ----
    {
        int eL = tid >> 3, h = tid & 7;
        if (eL < cnt) {
            int src = Ss[eL], dst = Ds[eL];
            const short* qp = &qb[(size_t)dst * 128 + h * 16];
            const short* kp = &kb[(size_t)src * 128 + h * 16];
            s16x8 q0 = *(const s16x8*)qp, q1 = *(const s16x8*)(qp + 8);
            s16x8 k0 = *(const s16x8*)kp, k1 = *(const s16x8*)(kp + 8);
            s16x8 ev0 = *(const s16x8*)&Es[eL][h * 16];
            s16x8 ev1 = *(const s16x8*)&Es[eL][h * 16 + 8];
            float a_val = 0.f;
#pragma unroll
            for (int c = 0; c < 8; c++) {
                a_val += bf2f(q0[c]) * (bf2f(k0[c]) + bf2f(ev0[c]));
                a_val += bf2f(q1[c]) * (bf2f(k1[c]) + bf2f(ev1[c]));
            }
            a_val *= 0.25f;                  // 1/sqrt(C), C=16
            // exp WITHOUT per-node max (cancels in p/sum p); clamp for inf-safety
            Pls[eL][h] = __expf(fminf(a_val, 60.f));
        }
    }
    __syncthreads();

    // ---- phase 3: PV — preloaded vb rows, register run-aggregation, atomic flush ----
    {
        int base = wave * 8;
        int h = lane >> 3;                   // head of this lane's channel pair
        unsigned vvr[8];
        int dr[8];
#pragma unroll
        for (int k = 0; k < 8; k++) {        // issue all 8 vb loads up front
            int eL = base + k;
            bool ok = (eL < cnt);
            int src = ok ? Ss[eL] : 0;
            dr[k] = ok ? Ds[eL] : -1;
            vvr[k] = *(const unsigned*)&vb[(size_t)src * 128 + lane * 2];
        }
        float c0 = 0.f, c1 = 0.f, pd = 0.f;
        int curd = -1;
#pragma unroll
        for (int k = 0; k < 8; k++) {
            int d = dr[k];
            if (d < 0) continue;
            if (d != curd) {                 // wave-uniform branch
                if (curd >= 0) {
                    atomicAdd(&outacc[(size_t)curd * 128 + lane * 2],     c0);
                    atomicAdd(&outacc[(size_t)curd * 128 + lane * 2 + 1], c1);
                    if ((lane & 7) == 0) atomicAdd(&denom[(size_t)curd * HEADS + h], pd);
                }
                c0 = c1 = pd = 0.f;
                curd = d;
            }
            int eL = base + k;
            float p = Pls[eL][h];                                   // LDS broadcast
            unsigned vv = vvr[k];
            unsigned ee = *(const unsigned*)&Es[eL][lane * 2];
            c0 += p * (bf2f((short)(vv & 0xffff)) + bf2f((short)(ee & 0xffff)));
            c1 += p * (bf2f((short)(vv >> 16))    + bf2f((short)(ee >> 16)));
            if ((lane & 7) == 0) pd += p;
        }
        if (curd >= 0) {
            atomicAdd(&outacc[(size_t)curd * 128 + lane * 2],     c0);
            atomicAdd(&outacc[(size_t)curd * 128 + lane * 2 + 1], c1);
            if ((lane & 7) == 0) atomicAdd(&denom[(size_t)curd * HEADS + h], pd);
        }
    }
}

// ---------------- kernel 3: finalize out = outacc/(denom+eps) + skip ----------------
__global__ void finalize(const float* __restrict__ outacc, const float* __restrict__ denom,
                         const float* __restrict__ skb, float* __restrict__ out, int total4) {
    int idx = blockIdx.x * 256 + threadIdx.x;
    if (idx >= total4) return;                 // total4 = N*32 (float4 units)
    int n = idx >> 5, q4 = idx & 31;
    int h = q4 >> 2;
    float inv = 1.f / (denom[(size_t)n * HEADS + h] + 1e-16f);
    float4 a = ((const float4*)outacc)[idx];
    float4 sk = ((const float4*)skb)[idx];
    float4 r = make_float4(a.x * inv + sk.x, a.y * inv + sk.y,
                           a.z * inv + sk.z, a.w * inv + sk.w);
    ((float4*)out)[idx] = r;
}

// ---------------- launch ----------------
extern "C" void kernel_launch(void* const* d_in, const int* in_sizes, int n_in,
                              void* d_out, int out_size, void* d_ws, size_t ws_size,
                              hipStream_t stream) {
    const float* x   = (const float*)d_in[0];
    const float* ea  = (const float*)d_in[1];
    const float* Wq  = (const float*)d_in[2];
    const float* bq  = (const float*)d_in[3];
    const float* Wk  = (const float*)d_in[4];
    const float* bk  = (const float*)d_in[5];
    const float* Wv  = (const float*)d_in[6];
    const float* bv  = (const float*)d_in[7];
    const float* We  = (const float*)d_in[8];
    const float* Wsk = (const float*)d_in[9];
    const float* bsk = (const float*)d_in[10];
    const int*   eidx = (const int*)d_in[11];

    int Nn = in_sizes[0] / 128;   // 50000
    int Ee = in_sizes[1] / 128;   // 800000
    float* out = (float*)d_out;

    // ws layout (outacc+denom adjacent; cnt+cursor adjacent -> merged memsets)
    size_t need = 0;
    size_t off_qb  = need; need += (size_t)Nn * 128 * 2;   // qb bf16
    size_t off_kb  = need; need += (size_t)Nn * 128 * 2;   // kb bf16
    size_t off_vb  = need; need += (size_t)Nn * 128 * 2;   // vb bf16
    size_t off_skb = need; need += (size_t)Nn * 128 * 4;   // skip f32
    size_t off_oa  = need; need += (size_t)Nn * 128 * 4;   // outacc f32
    size_t off_dn  = need; need += (size_t)Nn * HEADS * 4; // denom f32
    size_t off_perm= need; need += (size_t)Ee * 4;         // perm
    size_t off_src = need; need += (size_t)Ee * 4;         // srcs (perm order)
    size_t off_dst = need; need += (size_t)Ee * 4;         // dsts (perm order)
    size_t off_rp  = need; need += (size_t)(Nn + 1) * 4;   // rowptr
    size_t off_cnt = need; need += (size_t)Nn * 4;         // counts
    size_t off_cur = need; need += (size_t)Nn * 4;         // cursors
    size_t off_wt  = need; need += 5 * 16384 * 2;          // Wt5
    (void)need;

    char* ws = (char*)d_ws;
    short* qb    = (short*)(ws + off_qb);
    short* kb    = (short*)(ws + off_kb);
    short* vb    = (short*)(ws + off_vb);
    float* skb   = (float*)(ws + off_skb);
    float* outacc= (float*)(ws + off_oa);
    float* denom = (float*)(ws + off_dn);
    int*   perm  = (int*)(ws + off_perm);
    int*   srcs  = (int*)(ws + off_src);
    int*   dsts  = (int*)(ws + off_dst);
    int*   rowptr= (int*)(ws + off_rp);
    int*   cnt   = (int*)(ws + off_cnt);
    int*   cursor= (int*)(ws + off_cur);
    short* Wt5   = (short*)(ws + off_wt);

    // merged memsets (adjacent regions)
    hipMemsetAsync(outacc, 0, (size_t)Nn * 128 * 4 + (size_t)Nn * HEADS * 4, stream);
    hipMemsetAsync(cnt, 0, (size_t)Nn * 8, stream);   // cnt + cursor

    prep_w<<<(5 * 16384 + 255) / 256, 256, 0, stream>>>(Wq, Wk, Wv, We, Wsk, Wt5);
    hist_dst<<<(Ee + 255) / 256, 256, 0, stream>>>(eidx, cnt, Ee);
    scan_rowptr<<<1, 1024, 0, stream>>>(cnt, rowptr, Nn);
    fill_perm2<<<(Ee + 255) / 256, 256, 0, stream>>>(eidx, rowptr, cursor, perm, srcs, dsts, Ee);
    node_proj<<<(Nn + TILE_M - 1) / TILE_M, 512, 0, stream>>>(
        x, Wt5, bq, bk, bv, bsk, qb, kb, vb, skb, Nn);
    fused_edge<<<(Ee + TILE_M - 1) / TILE_M, 512, 0, stream>>>(
        ea, Wt5, qb, kb, vb, perm, srcs, dsts, outacc, denom, Ee);
    finalize<<<(Nn * 32 + 255) / 256, 256, 0, stream>>>(
        outacc, denom, skb, out, Nn * 32);
}